// Round 4
// baseline (42.304 us; speedup 1.0000x reference)
//
#include <hip/hip_runtime.h>
#include <hip/hip_bf16.h>

typedef __attribute__((ext_vector_type(8))) short short8_t;
typedef __attribute__((ext_vector_type(4))) float f32x4;

static __device__ __forceinline__ unsigned short f2bf(float f) {
    unsigned int u = __float_as_uint(f);
    unsigned int r = u + 0x7fffu + ((u >> 16) & 1u);   // RNE (finite inputs)
    return (unsigned short)(r >> 16);
}

#define BM 128
#define BN 64
#define LDA 136   // bf16 elems per LDS row: 128 + 8 pad

// Fused: stage f32 -> bf16 in LDS + row norms, MFMA, epilogue.
// out[m][c] = 2*dot(x[m],P[c]) - xsq[m] - psq[c]  (= -||x-P||^2), c < 1000.
__global__ __launch_bounds__(256) void fused_kernel(
        const float* __restrict__ X,   // [8192][128] f32
        const float* __restrict__ P,   // [1000][128] f32
        float* __restrict__ out) {     // [8192][1000] f32
    __shared__ unsigned short As[BM][LDA];
    __shared__ unsigned short Bs[BN][LDA];
    __shared__ float xq_s[BM];
    __shared__ float pq_s[BN];

    int t = threadIdx.x;
    int bn = blockIdx.x & 15;
    int bm = blockIdx.x >> 4;
    const int rowA0 = bm * BM;
    const int rowB0 = bn * BN;

    #pragma unroll
    for (int it = 0; it < 8; ++it) {
        int idx = it * 256 + t;
        int r = idx >> 4;
        int c8 = (idx & 15) * 8;
        const float4* src = reinterpret_cast<const float4*>(X + (size_t)(rowA0 + r) * 128 + c8);
        float4 v0 = src[0], v1 = src[1];
        short8_t b;
        b[0] = (short)f2bf(v0.x); b[1] = (short)f2bf(v0.y);
        b[2] = (short)f2bf(v0.z); b[3] = (short)f2bf(v0.w);
        b[4] = (short)f2bf(v1.x); b[5] = (short)f2bf(v1.y);
        b[6] = (short)f2bf(v1.z); b[7] = (short)f2bf(v1.w);
        *reinterpret_cast<short8_t*>(&As[r][c8]) = b;
        float s = v0.x*v0.x + v0.y*v0.y + v0.z*v0.z + v0.w*v0.w
                + v1.x*v1.x + v1.y*v1.y + v1.z*v1.z + v1.w*v1.w;
        s += __shfl_xor(s, 1, 64);
        s += __shfl_xor(s, 2, 64);
        s += __shfl_xor(s, 4, 64);
        s += __shfl_xor(s, 8, 64);
        if ((t & 15) == 0) xq_s[r] = s;
    }
    #pragma unroll
    for (int it = 0; it < 4; ++it) {
        int idx = it * 256 + t;
        int r = idx >> 4;
        int c8 = (idx & 15) * 8;
        int gr = rowB0 + r;
        float4 v0 = make_float4(0.f, 0.f, 0.f, 0.f);
        float4 v1 = make_float4(0.f, 0.f, 0.f, 0.f);
        if (gr < 1000) {
            const float4* src = reinterpret_cast<const float4*>(P + (size_t)gr * 128 + c8);
            v0 = src[0]; v1 = src[1];
        }
        short8_t b;
        b[0] = (short)f2bf(v0.x); b[1] = (short)f2bf(v0.y);
        b[2] = (short)f2bf(v0.z); b[3] = (short)f2bf(v0.w);
        b[4] = (short)f2bf(v1.x); b[5] = (short)f2bf(v1.y);
        b[6] = (short)f2bf(v1.z); b[7] = (short)f2bf(v1.w);
        *reinterpret_cast<short8_t*>(&Bs[r][c8]) = b;
        float s = v0.x*v0.x + v0.y*v0.y + v0.z*v0.z + v0.w*v0.w
                + v1.x*v1.x + v1.y*v1.y + v1.z*v1.z + v1.w*v1.w;
        s += __shfl_xor(s, 1, 64);
        s += __shfl_xor(s, 2, 64);
        s += __shfl_xor(s, 4, 64);
        s += __shfl_xor(s, 8, 64);
        if ((t & 15) == 0) pq_s[r] = s;
    }
    __syncthreads();

    int wave = t >> 6;
    int lane = t & 63;
    int wm = (wave >> 1) * 64;
    int wn = (wave & 1) * 32;
    int lr = lane & 15;
    int lk = (lane >> 4) * 8;

    f32x4 acc[4][2] = {};
    #pragma unroll
    for (int ks = 0; ks < 4; ++ks) {
        int k0 = ks * 32 + lk;
        short8_t a[4], b[2];
        #pragma unroll
        for (int mi = 0; mi < 4; ++mi)
            a[mi] = *reinterpret_cast<const short8_t*>(&As[wm + mi * 16 + lr][k0]);
        #pragma unroll
        for (int ni = 0; ni < 2; ++ni)
            b[ni] = *reinterpret_cast<const short8_t*>(&Bs[wn + ni * 16 + lr][k0]);
        #pragma unroll
        for (int mi = 0; mi < 4; ++mi)
            #pragma unroll
            for (int ni = 0; ni < 2; ++ni)
                acc[mi][ni] = __builtin_amdgcn_mfma_f32_16x16x32_bf16(
                        a[mi], b[ni], acc[mi][ni], 0, 0, 0);
    }

    int mrow_base = (lane >> 4) * 4;
    #pragma unroll
    for (int mi = 0; mi < 4; ++mi) {
        #pragma unroll
        for (int ni = 0; ni < 2; ++ni) {
            int cl = wn + ni * 16 + lr;
            int c = rowB0 + cl;
            if (c < 1000) {
                float pq = pq_s[cl];
                #pragma unroll
                for (int j = 0; j < 4; ++j) {
                    int ml = wm + mi * 16 + mrow_base + j;
                    int m = rowA0 + ml;
                    out[(size_t)m * 1000 + c] = 2.f * acc[mi][ni][j] - xq_s[ml] - pq;
                }
            }
        }
    }
}

extern "C" void kernel_launch(void* const* d_in, const int* in_sizes, int n_in,
                              void* d_out, int out_size, void* d_ws, size_t ws_size,
                              hipStream_t stream) {
    const float* x = (const float*)d_in[0];   // (8192, 128) f32
    const float* p = (const float*)d_in[1];   // (1000, 128) f32
    float* out = (float*)d_out;               // (8192, 1000) f32
    (void)d_ws; (void)ws_size;
    // CALIBRATION: launch the identical kernel twice (second write is identical,
    // output unchanged). Distinguishes fixed measurement overhead (~+6us) from
    // real kernel time (~2x).
    fused_kernel<<<1024, 256, 0, stream>>>(x, p, out);
    fused_kernel<<<1024, 256, 0, stream>>>(x, p, out);
}

// Round 6
// 28.142 us; speedup vs baseline: 1.5032x; 1.5032x over previous
//
#include <hip/hip_runtime.h>
#include <hip/hip_bf16.h>

typedef __attribute__((ext_vector_type(8))) short short8_t;
typedef __attribute__((ext_vector_type(4))) float f32x4;

static __device__ __forceinline__ unsigned short f2bf(float f) {
    unsigned int u = __float_as_uint(f);
    unsigned int r = u + 0x7fffu + ((u >> 16) & 1u);   // RNE (finite inputs)
    return (unsigned short)(r >> 16);
}

// Convert f32 [rows_valid][128] -> bf16 [rows_total][128] (zero-padded), plus f32 row norms.
__global__ __launch_bounds__(256) void prep_kernel(
        const float* __restrict__ src, unsigned short* __restrict__ dst,
        float* __restrict__ sq, int rows_valid, int rows_total) {
    int t = threadIdx.x;
    int row = blockIdx.x * 8 + (t >> 5);
    int lane32 = t & 31;
    if (row >= rows_total) return;
    float4 v = make_float4(0.f, 0.f, 0.f, 0.f);
    if (row < rows_valid)
        v = reinterpret_cast<const float4*>(src + (size_t)row * 128)[lane32];
    ushort4 b;
    b.x = f2bf(v.x); b.y = f2bf(v.y); b.z = f2bf(v.z); b.w = f2bf(v.w);
    reinterpret_cast<ushort4*>(dst + (size_t)row * 128)[lane32] = b;
    float s = v.x*v.x + v.y*v.y + v.z*v.z + v.w*v.w;
    #pragma unroll
    for (int m = 16; m >= 1; m >>= 1) s += __shfl_xor(s, m, 64);
    if (lane32 == 0) sq[row] = s;
}

#define LDB 132        // bf16 elems per LDS row: 264B stride -> 2-way (free) frag reads
#define OSTRIDE 1008   // f32 per out_s row; +8-per-row-group rotation keeps banks 2-way

// Block owns a 32-row output slab (contiguous 128000B, 128B-aligned). Computes the
// whole slab into LDS, then stores it as contiguous full-line runs (no partial lines).
__global__ __launch_bounds__(512) void main_kernel(
        const float* __restrict__ X,             // [8192][128] f32
        const unsigned short* __restrict__ Bw,   // [1024][128] bf16 bits (padded)
        const float* __restrict__ psq,           // [1024] f32
        float* __restrict__ out) {               // [8192][1000] f32
    extern __shared__ float dynlds[];            // out_s[32][OSTRIDE]; prologue aliases As
    unsigned short (*As)[LDB] = reinterpret_cast<unsigned short(*)[LDB]>(dynlds);
    float* out_s = dynlds;
    __shared__ unsigned short Bs[64][LDB];       // single-buffered (LDS headroom)
    __shared__ float xq_s[32];

    const int t = threadIdx.x;
    const int slab0 = blockIdx.x * 32;

    // ---- prologue: stage A (32x128 f32->bf16, aliased region) + row norms ----
    {
        int r = t >> 4;                  // 16 threads per row, 32 rows
        int c8 = (t & 15) * 8;
        const float4* src = reinterpret_cast<const float4*>(X + (size_t)(slab0 + r) * 128 + c8);
        float4 v0 = src[0], v1 = src[1];
        short8_t b;
        b[0] = (short)f2bf(v0.x); b[1] = (short)f2bf(v0.y);
        b[2] = (short)f2bf(v0.z); b[3] = (short)f2bf(v0.w);
        b[4] = (short)f2bf(v1.x); b[5] = (short)f2bf(v1.y);
        b[6] = (short)f2bf(v1.z); b[7] = (short)f2bf(v1.w);
        *reinterpret_cast<short8_t*>(&As[r][c8]) = b;
        float s = v0.x*v0.x + v0.y*v0.y + v0.z*v0.z + v0.w*v0.w
                + v1.x*v1.x + v1.y*v1.y + v1.z*v1.z + v1.w*v1.w;
        s += __shfl_xor(s, 1, 64);
        s += __shfl_xor(s, 2, 64);
        s += __shfl_xor(s, 4, 64);
        s += __shfl_xor(s, 8, 64);
        if ((t & 15) == 0) xq_s[r] = s;
    }
    // ---- stage B tile 0 ----
    {
        int r = t >> 3;                  // 64 rows, 8 threads/row, 16 elems/thread
        int c = (t & 7) * 16;
        const unsigned short* src = Bw + (size_t)r * 128 + c;
        *reinterpret_cast<short8_t*>(&Bs[r][c])     = *reinterpret_cast<const short8_t*>(src);
        *reinterpret_cast<short8_t*>(&Bs[r][c + 8]) = *reinterpret_cast<const short8_t*>(src + 8);
    }
    __syncthreads();

    const int wave  = t >> 6;
    const int lane  = t & 63;
    const int wm    = (wave >> 2) * 16;   // row group: 0 / 16
    const int wn    = (wave & 3) * 16;    // col group within 64-col tile
    const int lr    = lane & 15;
    const int lkb   = (lane >> 4) * 8;
    const int rbase = (lane >> 4) * 4;

    short8_t afrag[4];
    #pragma unroll
    for (int ks = 0; ks < 4; ++ks)
        afrag[ks] = *reinterpret_cast<const short8_t*>(&As[wm + lr][ks * 32 + lkb]);
    __syncthreads();   // As alias retired; out_s live from here

    #pragma unroll 1
    for (int cn = 0; cn < 16; ++cn) {
        // Prefetch next B tile to registers (hides under compute).
        short8_t pf0, pf1;
        if (cn < 15) {
            int r = t >> 3, c = (t & 7) * 16;
            const unsigned short* src = Bw + (size_t)((cn + 1) * 64 + r) * 128 + c;
            pf0 = *reinterpret_cast<const short8_t*>(src);
            pf1 = *reinterpret_cast<const short8_t*>(src + 8);
        }
        f32x4 acc = {0.f, 0.f, 0.f, 0.f};
        #pragma unroll
        for (int ks = 0; ks < 4; ++ks) {
            short8_t bfrag = *reinterpret_cast<const short8_t*>(
                    &Bs[wn + lr][ks * 32 + lkb]);
            acc = __builtin_amdgcn_mfma_f32_16x16x32_bf16(afrag[ks], bfrag, acc, 0, 0, 0);
        }
        // Epilogue into LDS slab: 2*acc - pq (xq folded at final store).
        // C/D layout: col=lane&15, row=(lane>>4)*4+j  [m89]
        int col = cn * 64 + wn + lr;
        if (col < 1000) {
            float pq = psq[col];
            #pragma unroll
            for (int j = 0; j < 4; ++j) {
                int row = wm + rbase + j;
                int pc = col + ((row >> 2) & 3) * 8;   // rotation: 2-way banks max
                if (pc >= OSTRIDE) pc -= OSTRIDE;
                out_s[row * OSTRIDE + pc] = 2.f * acc[j] - pq;
            }
        }
        if (cn < 15) {
            __syncthreads();   // all reads of Bs done
            int r = t >> 3, c = (t & 7) * 16;
            *reinterpret_cast<short8_t*>(&Bs[r][c])     = pf0;
            *reinterpret_cast<short8_t*>(&Bs[r][c + 8]) = pf1;
            __syncthreads();   // new tile visible
        }
    }
    __syncthreads();

    // ---- store pass: contiguous, line-aligned slab write (full lines only) ----
    #pragma unroll
    for (int ri = 0; ri < 4; ++ri) {
        int r = wave * 4 + ri;
        float xq = xq_s[r];
        int sw = ((r >> 2) & 3) * 8;
        size_t gbase = (size_t)(slab0 + r) * 1000;
        #pragma unroll
        for (int seg = 0; seg < 4; ++seg) {
            int c = seg * 256 + lane * 4;
            if (c < 1000) {
                int pc = c + sw;
                if (pc >= OSTRIDE) pc -= OSTRIDE;
                f32x4 v = *reinterpret_cast<const f32x4*>(&out_s[r * OSTRIDE + pc]);
                float4 o = make_float4(v[0] - xq, v[1] - xq, v[2] - xq, v[3] - xq);
                *reinterpret_cast<float4*>(out + gbase + c) = o;
            }
        }
    }
}

// Correct-but-slow fallback.
__global__ __launch_bounds__(256) void naive_kernel(
        const float* __restrict__ x, const float* __restrict__ p,
        float* __restrict__ out) {
    long long idx = (long long)blockIdx.x * 256 + threadIdx.x;
    if (idx >= (long long)8192 * 1000) return;
    int n = (int)(idx / 1000);
    int c = (int)(idx % 1000);
    const float4* xr = reinterpret_cast<const float4*>(x + (size_t)n * 128);
    const float4* pr = reinterpret_cast<const float4*>(p + (size_t)c * 128);
    float d = 0.f;
    #pragma unroll
    for (int i = 0; i < 32; ++i) {
        float4 a = xr[i], b = pr[i];
        float dx = a.x - b.x, dy = a.y - b.y, dz = a.z - b.z, dw = a.w - b.w;
        d += dx * dx + dy * dy + dz * dz + dw * dw;
    }
    out[idx] = -d;
}

extern "C" void kernel_launch(void* const* d_in, const int* in_sizes, int n_in,
                              void* d_out, int out_size, void* d_ws, size_t ws_size,
                              hipStream_t stream) {
    const float* x = (const float*)d_in[0];   // (8192, 128) f32
    const float* p = (const float*)d_in[1];   // (1000, 128) f32
    float* out = (float*)d_out;               // (8192, 1000) f32

    const size_t pb_elems = (size_t)1024 * 128;
    const size_t need = pb_elems * 2 + 1024 * 4;
    const int dyn_bytes = 32 * OSTRIDE * 4;   // 129024 dyn + ~17KB static = ~146KB

    hipError_t attr_ok = hipFuncSetAttribute(
            (const void*)main_kernel,
            hipFuncAttributeMaxDynamicSharedMemorySize, dyn_bytes);

    if (ws_size >= need && attr_ok == hipSuccess) {
        unsigned short* pb = (unsigned short*)d_ws;
        float* psq = (float*)(pb + pb_elems);
        prep_kernel<<<128, 256, 0, stream>>>(p, pb, psq, 1000, 1024);
        main_kernel<<<256, 512, dyn_bytes, stream>>>(x, pb, psq, out);
    } else {
        naive_kernel<<<((size_t)8192 * 1000 + 255) / 256, 256, 0, stream>>>(x, p, out);
    }
}